// Round 9
// baseline (298.085 us; speedup 1.0000x reference)
//
#include <hip/hip_runtime.h>
#include <math.h>

#define BB   32      // batch
#define NN   1024    // nodes
#define DIN  2
#define DOUT 64
#define CIN  66      // DIN + DOUT
#define TD   32
#define ED   10
#define OG   128     // 2*DOUT (gate out)
#define OU   64      // upd out
#define KP   160     // padded K for the einsum GEMM (132 real)
#define XTR  80      // XT rows per batch (68 data + 12 zero pad)

typedef __bf16 bf16x8 __attribute__((ext_vector_type(8)));
typedef float  f32x4  __attribute__((ext_vector_type(4)));
typedef short  s16x8  __attribute__((ext_vector_type(8)));

__device__ __forceinline__ unsigned short f2b(float f) {
    __bf16 h = (__bf16)f;
    return *(unsigned short*)&h;
}

// pack two f32 -> two bf16 (RNE), lo in low half
__device__ __forceinline__ unsigned int cvt_pk_bf16(float lo, float hi) {
    unsigned int r;
    asm("v_cvt_pk_bf16_f32 %0, %1, %2" : "=v"(r) : "v"(lo), "v"(hi));
    return r;
}
// a' = {a.lo32, b.lo32}; b' = {a.hi32, b.hi32}
__device__ __forceinline__ void perm32swap(unsigned int& a, unsigned int& b) {
    asm("v_permlane32_swap_b32 %0, %1" : "+v"(a), "+v"(b));
}
// a' = {a.r0, b.r0, a.r2, b.r2}; b' = {a.r1, b.r1, a.r3, b.r3} (16-lane rows)
__device__ __forceinline__ void perm16swap(unsigned int& a, unsigned int& b) {
    asm("v_permlane16_swap_b32 %0, %1" : "+v"(a), "+v"(b));
}

// B-panel prefetch helpers (R3-validated indexing)
__device__ __forceinline__ void loadB(
    const unsigned short* __restrict__ BcT, int O, int o0, int h, int t,
    uint4 (&pr)[7])
{
    #pragma unroll
    for (int k = 0; k < 7; ++k) {
        int i = k*256 + t;
        if (i < 1600) {
            int cc = i/20, kc = i - cc*20;
            int d = h*5 + (cc >> 4), oo = cc & 15;
            pr[k] = *(const uint4*)&BcT[(size_t)(d*O + o0 + oo)*KP + kc*8];
        }
    }
}
__device__ __forceinline__ void writeB(unsigned short* sb, int t, const uint4 (&pr)[7])
{
    #pragma unroll
    for (int k = 0; k < 7; ++k) {
        int i = k*256 + t;
        if (i < 1600) {
            int cc = i/20, kc = i - cc*20;
            *(uint4*)&sb[cc*168 + kc*8] = pr[k];
        }
    }
}

// ---------------------------------------------------------------------------
// K_PRE (R2-exact): heterogeneous preprocessing, one dispatch. FROZEN.
// ---------------------------------------------------------------------------
__global__ __launch_bounds__(256) void k_pre(
    const float* __restrict__ x, const float* __restrict__ state,
    const float* __restrict__ ne0, const float* __restrict__ ne1,
    const float* __restrict__ ne2,
    const float* __restrict__ w11, const float* __restrict__ b11,
    const float* __restrict__ w12, const float* __restrict__ b12,
    const float* __restrict__ w13, const float* __restrict__ b13,
    const float* __restrict__ w21, const float* __restrict__ b21,
    const float* __restrict__ w22, const float* __restrict__ b22,
    const float* __restrict__ w23, const float* __restrict__ b23,
    const float* __restrict__ gate_w, const float* __restrict__ gate_b,
    const float* __restrict__ upd_w, const float* __restrict__ upd_b,
    unsigned short* __restrict__ nv1b, unsigned short* __restrict__ nv2b,
    unsigned short* __restrict__ XT0, unsigned short* __restrict__ XT1,
    unsigned short* __restrict__ BcTg, unsigned short* __restrict__ BcTu,
    float* __restrict__ biasG, float* __restrict__ biasU)
{
    __shared__ float sw[2408];
    __shared__ unsigned short st[68*72];
    int blk = blockIdx.x;
    int t = threadIdx.x;

    if (blk < 128) {
        const int oW1 = 0, oB1 = 1056, oW2 = 1072, oB2 = 1104, oW3 = 1108, oB3 = 1172, F2 = 1204;
        for (int i = t; i < 1056; i += 256) { sw[oW1+i] = w11[i]; sw[F2+oW1+i] = w21[i]; }
        if (t < 16) { sw[oB1+t] = b11[t]; sw[F2+oB1+t] = b21[t]; }
        if (t < 32) { sw[oW2+t] = w12[t]; sw[F2+oW2+t] = w22[t]; }
        if (t < 2)  { sw[oB2+t] = b12[t]; sw[F2+oB2+t] = b22[t]; }
        if (t < 64) { sw[oW3+t] = w13[t]; sw[F2+oW3+t] = w23[t]; }
        if (t >= 64 && t < 96) { sw[oB3+t-64] = b13[t-64]; sw[F2+oB3+t-64] = b23[t-64]; }
        __syncthreads();

        int p = blk*256 + t;
        int b = p >> 10;

        float h1a[16], h1b[16];
        #pragma unroll
        for (int j = 0; j < 16; ++j) { h1a[j] = sw[oB1+j]; h1b[j] = sw[F2+oB1+j]; }
        for (int i = 0; i < CIN; ++i) {
            float v = (i < DIN) ? x[(size_t)p*DIN + i] : state[(size_t)p*DOUT + (i-DIN)];
            #pragma unroll
            for (int jq = 0; jq < 4; ++jq) {
                float4 wa = *(const float4*)&sw[oW1 + i*16 + jq*4];
                float4 wb = *(const float4*)&sw[F2 + oW1 + i*16 + jq*4];
                h1a[jq*4+0] += v*wa.x; h1a[jq*4+1] += v*wa.y;
                h1a[jq*4+2] += v*wa.z; h1a[jq*4+3] += v*wa.w;
                h1b[jq*4+0] += v*wb.x; h1b[jq*4+1] += v*wb.y;
                h1b[jq*4+2] += v*wb.z; h1b[jq*4+3] += v*wb.w;
            }
        }
        #pragma unroll
        for (int j = 0; j < 16; ++j) {
            h1a[j] = 1.f/(1.f + __expf(-h1a[j]));
            h1b[j] = 1.f/(1.f + __expf(-h1b[j]));
        }
        float h2a0 = sw[oB2+0], h2a1 = sw[oB2+1];
        float h2b0 = sw[F2+oB2+0], h2b1 = sw[F2+oB2+1];
        #pragma unroll
        for (int i = 0; i < 16; ++i) {
            h2a0 += h1a[i]*sw[oW2 + i*2 + 0];
            h2a1 += h1a[i]*sw[oW2 + i*2 + 1];
            h2b0 += h1b[i]*sw[F2+oW2 + i*2 + 0];
            h2b1 += h1b[i]*sw[F2+oW2 + i*2 + 1];
        }
        h2a0 = 1.f/(1.f + __expf(-h2a0)); h2a1 = 1.f/(1.f + __expf(-h2a1));
        h2b0 = 1.f/(1.f + __expf(-h2b0)); h2b1 = 1.f/(1.f + __expf(-h2b1));

        const float* pn0 = ne0 + b*TD;
        const float* pn1 = ne1 + b*TD;
        #pragma unroll
        for (int jq = 0; jq < 8; ++jq) {
            float4 ba  = *(const float4*)&sw[oB3 + jq*4];
            float4 wa0 = *(const float4*)&sw[oW3 + jq*4];
            float4 wa1 = *(const float4*)&sw[oW3 + 32 + jq*4];
            float4 bb2 = *(const float4*)&sw[F2+oB3 + jq*4];
            float4 wb0 = *(const float4*)&sw[F2+oW3 + jq*4];
            float4 wb1 = *(const float4*)&sw[F2+oW3 + 32 + jq*4];
            float4 n0 = *(const float4*)&pn0[jq*4];
            float4 n1 = *(const float4*)&pn1[jq*4];
            ushort4 u1, u2;
            u1.x = f2b(tanhf(n0.x*(ba.x + h2a0*wa0.x + h2a1*wa1.x)));
            u1.y = f2b(tanhf(n0.y*(ba.y + h2a0*wa0.y + h2a1*wa1.y)));
            u1.z = f2b(tanhf(n0.z*(ba.z + h2a0*wa0.z + h2a1*wa1.z)));
            u1.w = f2b(tanhf(n0.w*(ba.w + h2a0*wa0.w + h2a1*wa1.w)));
            u2.x = f2b(tanhf(n1.x*(bb2.x + h2b0*wb0.x + h2b1*wb1.x)));
            u2.y = f2b(tanhf(n1.y*(bb2.y + h2b0*wb0.y + h2b1*wb1.y)));
            u2.z = f2b(tanhf(n1.z*(bb2.z + h2b0*wb0.z + h2b1*wb1.z)));
            u2.w = f2b(tanhf(n1.w*(bb2.w + h2b0*wb0.w + h2b1*wb1.w)));
            *(ushort4*)&nv1b[(size_t)p*TD + jq*4] = u1;
            *(ushort4*)&nv2b[(size_t)p*TD + jq*4] = u2;
        }
    } else if (blk < 640) {
        int idx = blk - 128;
        int b = idx >> 4, m0 = (idx & 15)*64;
        for (int i = t; i < 1024; i += 256) {
            int m = i >> 4, cq = i & 15;
            size_t base = (size_t)b*NN + m0 + m;
            float4 v = *(const float4*)&state[base*DOUT + cq*4];
            st[(2 + cq*4 + 0)*72 + m] = f2b(v.x);
            st[(2 + cq*4 + 1)*72 + m] = f2b(v.y);
            st[(2 + cq*4 + 2)*72 + m] = f2b(v.z);
            st[(2 + cq*4 + 3)*72 + m] = f2b(v.w);
        }
        if (t < 128) {
            int m = t >> 1, c = t & 1;
            st[c*72 + m] = f2b(x[((size_t)b*NN + m0 + m)*DIN + c]);
        }
        __syncthreads();
        const unsigned int ONE2 = 0x3F803F80u;
        for (int i = t; i < XTR*8; i += 256) {
            int c = i >> 3, ch = i & 7;
            uint4 v;
            if (c < 66)      v = *(const uint4*)&st[c*72 + ch*8];
            else if (c == 66) v = make_uint4(ONE2, ONE2, ONE2, ONE2);
            else              v = make_uint4(0, 0, 0, 0);
            *(uint4*)&XT0[((size_t)b*XTR + c)*NN + m0 + ch*8] = v;
            if (c < 2 || c >= 66)
                *(uint4*)&XT1[((size_t)b*XTR + c)*NN + m0 + ch*8] = v;
        }
    } else if (blk < 1840) {
        int tid = (blk - 640)*256 + t;
        int c = tid / KP, k = tid - c*KP;
        const float* pool; int O, cc; unsigned short* dst;
        if (c < 1280) { pool = gate_w; O = OG; cc = c;        dst = BcTg; }
        else          { pool = upd_w;  O = OU; cc = c - 1280; dst = BcTu; }
        int d = cc / O, o = cc - d*O;
        float v = 0.f;
        if (k < 132) {
            int kp = (k < 66) ? 0 : 1;
            int i  = (k < 66) ? k : k - 66;
            v = pool[(size_t)((d*4 + kp)*CIN + i)*O + o]
              + pool[(size_t)((d*4 + kp + 2)*CIN + i)*O + o];
        }
        dst[(size_t)cc*KP + k] = f2b(v);
    } else {
        int i = (blk - 1840)*256 + t;
        int n = i / 192, j = i - n*192;
        float v = 0.f;
        if (j < 128) {
            #pragma unroll
            for (int d = 0; d < ED; ++d) v += ne2[(size_t)n*ED + d]*gate_b[d*OG + j];
            biasG[(size_t)n*OG + j] = v;
        } else {
            int o = j - 128;
            #pragma unroll
            for (int d = 0; d < ED; ++d) v += ne2[(size_t)n*ED + d]*upd_b[d*OU + o];
            biasU[(size_t)n*OU + o] = v;
        }
    }
}

// ---------------------------------------------------------------------------
// K_FUSED v2 = flash (aapply v8, proven) + PIPELINED gemm phase:
//   s_B double-buffered (2 x 26.9 KB) with depth-2 register prefetch and ONE
//   barrier per half (exact aapply-v8 schedule); A-fragments and ne2 rows
//   hoisted out of the 16-half loop (s_A immutable; occupancy is LDS-capped
//   at 2 blocks/CU so the extra VGPRs are free).
//   LDS = 10752 + 2*13440 = 37632 shorts = 75.3 KB -> 2 blocks/CU.
// ---------------------------------------------------------------------------
template<int O, int MODE>
__global__ __launch_bounds__(256) void k_fused(
    const unsigned short* __restrict__ nv1b, const unsigned short* __restrict__ nv2b,
    const unsigned short* __restrict__ XTg, const unsigned short* __restrict__ BcT,
    const float* __restrict__ ne2, const float* __restrict__ biasP,
    const float* __restrict__ state, unsigned short* __restrict__ XT1,
    float* __restrict__ rbuf, float* __restrict__ out)
{
    __shared__ unsigned short smem[37632];       // 75.3 KB
    // flash carve:  s_nv1c [2][2560] @0, s_nv2c @5120, s_xt [2][5760] @10240
    // gemm carve:   s_A [64][168] @0, s_B [2][80][168] @10752
    unsigned short* s_nv1c = smem;
    unsigned short* s_nv2c = smem + 5120;
    unsigned short* s_xt   = smem + 10240;

    int t = threadIdx.x;
    int id = blockIdx.x;
    int b = id & 31, rbase = (id >> 5)*64;
    int w = t >> 6, lane = t & 63, lq = lane >> 4, ln = lane & 15;

    // ======================= FLASH PHASE (aapply v8) =======================
    bf16x8 a1 = *(const bf16x8*)&nv1b[((size_t)b*NN + rbase + 16*w + ln)*TD + lq*8];
    s16x8 a2s = *(const s16x8*)&nv2b[((size_t)b*NN + rbase + 16*w + ln)*TD + lq*8];
    const s16x8 sgn = {(short)0x8000,(short)0x8000,(short)0x8000,(short)0x8000,
                       (short)0x8000,(short)0x8000,(short)0x8000,(short)0x8000};
    a2s ^= sgn;
    bf16x8 a2n = (bf16x8)a2s;          // -nv2 row fragment

    const unsigned short* pnv1 = nv1b + (size_t)b*NN*TD;
    const unsigned short* pnv2 = nv2b + (size_t)b*NN*TD;
    const unsigned short* pxt  = XTg  + (size_t)b*XTR*NN;
    int nnode = t >> 2;          // 0..63
    int nch   = (t & 3)*8;       // short offset 0,8,16,24
    int xc    = t >> 3;          // 0..31
    int xch   = (t & 7)*8;       // short offset 0..56

    uint4 q0, q1, r0, r1, r2;

    f32x4 acc[5];
    #pragma unroll
    for (int k = 0; k < 5; ++k) acc[k] = (f32x4){0.f,0.f,0.f,0.f};
    const f32x4 zero4 = {0.f,0.f,0.f,0.f};
    union U8 { unsigned int u[4]; bf16x8 v; };

    // prologue: tile 0 -> buf0 (direct), tile 1 -> regs
    q0 = *(const uint4*)&pnv1[(size_t)nnode*TD + nch];
    q1 = *(const uint4*)&pnv2[(size_t)nnode*TD + nch];
    r0 = *(const uint4*)&pxt[(size_t)xc*NN + xch];
    r1 = *(const uint4*)&pxt[(size_t)(xc+32)*NN + xch];
    if (t < 128) r2 = *(const uint4*)&pxt[(size_t)(xc+64)*NN + xch];
    *(uint4*)&s_nv1c[nnode*40 + nch] = q0;
    *(uint4*)&s_nv2c[nnode*40 + nch] = q1;
    *(uint4*)&s_xt[xc*72 + xch] = r0;
    *(uint4*)&s_xt[(xc+32)*72 + xch] = r1;
    if (t < 128) *(uint4*)&s_xt[(xc+64)*72 + xch] = r2;
    q0 = *(const uint4*)&pnv1[(size_t)(64 + nnode)*TD + nch];
    q1 = *(const uint4*)&pnv2[(size_t)(64 + nnode)*TD + nch];
    r0 = *(const uint4*)&pxt[(size_t)xc*NN + 64 + xch];
    r1 = *(const uint4*)&pxt[(size_t)(xc+32)*NN + 64 + xch];
    if (t < 128) r2 = *(const uint4*)&pxt[(size_t)(xc+64)*NN + 64 + xch];
    __syncthreads();

    int cur = 0;
    for (int mb = 0; mb < NN; mb += 64) {
        if (mb + 64 < NN) {
            int nx = cur ^ 1;
            *(uint4*)&s_nv1c[nx*2560 + nnode*40 + nch] = q0;
            *(uint4*)&s_nv2c[nx*2560 + nnode*40 + nch] = q1;
            *(uint4*)&s_xt[nx*5760 + xc*72 + xch] = r0;
            *(uint4*)&s_xt[nx*5760 + (xc+32)*72 + xch] = r1;
            if (t < 128) *(uint4*)&s_xt[nx*5760 + (xc+64)*72 + xch] = r2;
        }
        if (mb + 128 < NN) {
            int mb2 = mb + 128;
            q0 = *(const uint4*)&pnv1[(size_t)(mb2 + nnode)*TD + nch];
            q1 = *(const uint4*)&pnv2[(size_t)(mb2 + nnode)*TD + nch];
            r0 = *(const uint4*)&pxt[(size_t)xc*NN + mb2 + xch];
            r1 = *(const uint4*)&pxt[(size_t)(xc+32)*NN + mb2 + xch];
            if (t < 128) r2 = *(const uint4*)&pxt[(size_t)(xc+64)*NN + mb2 + xch];
        }

        unsigned int u[4][2];
        #pragma unroll
        for (int jj = 0; jj < 4; ++jj) {
            bf16x8 b2 = *(const bf16x8*)&s_nv2c[cur*2560 + (jj*16 + ln)*40 + lq*8];
            bf16x8 b1 = *(const bf16x8*)&s_nv1c[cur*2560 + (jj*16 + ln)*40 + lq*8];
            f32x4 s = __builtin_amdgcn_mfma_f32_16x16x32_bf16(b2, a1,  zero4, 0, 0, 0);
            s       = __builtin_amdgcn_mfma_f32_16x16x32_bf16(b1, a2n, s,     0, 0, 0);
            u[jj][0] = cvt_pk_bf16(fmaxf(s[0], 0.f), fmaxf(s[1], 0.f));
            u[jj][1] = cvt_pk_bf16(fmaxf(s[2], 0.f), fmaxf(s[3], 0.f));
        }

        unsigned int w00 = u[0][0], w20 = u[1][0]; perm32swap(w00, w20); perm16swap(w00, w20);
        unsigned int w01 = u[0][1], w21 = u[1][1]; perm32swap(w01, w21); perm16swap(w01, w21);
        unsigned int x00 = u[2][0], x20 = u[3][0]; perm32swap(x00, x20); perm16swap(x00, x20);
        unsigned int x01 = u[2][1], x21 = u[3][1]; perm32swap(x01, x21); perm16swap(x01, x21);
        U8 p0, p1;
        p0.u[0] = w00; p0.u[1] = w01; p0.u[2] = w20; p0.u[3] = w21;
        p1.u[0] = x00; p1.u[1] = x01; p1.u[2] = x20; p1.u[3] = x21;
        bf16x8 pa0 = p0.v, pa1 = p1.v;

        #pragma unroll
        for (int k = 0; k < 5; ++k) {
            bf16x8 xb0 = *(const bf16x8*)&s_xt[cur*5760 + (k*16 + ln)*72 +      lq*8];
            bf16x8 xb1 = *(const bf16x8*)&s_xt[cur*5760 + (k*16 + ln)*72 + 32 + lq*8];
            acc[k] = __builtin_amdgcn_mfma_f32_16x16x32_bf16(pa0, xb0, acc[k], 0, 0, 0);
            acc[k] = __builtin_amdgcn_mfma_f32_16x16x32_bf16(pa1, xb1, acc[k], 0, 0, 0);
        }

        __syncthreads();
        cur ^= 1;
    }

    // rowsum broadcast
    float rinv[4];
    #pragma unroll
    for (int r = 0; r < 4; ++r) {
        float rs = __shfl(acc[4][r], (lane & 48) | 2, 64);
        rinv[r] = 1.0f / (1.0f + rs);
    }

    // ============== A-TILE -> LDS (re-carve staging buffers) ==============
    unsigned short* s_A = smem;            // [64][168]
    unsigned short* s_B = smem + 10752;    // [2][80][168]

    for (int i = t; i < 64*28; i += 256) {             // zero pad cols 132..159
        int rr = i / 28, cc = 132 + (i - 28*(i/28));
        s_A[rr*168 + cc] = 0;
    }
    #pragma unroll
    for (int k = 0; k < 5; ++k) {
        int c = k*16 + ln;
        if (c < CIN) {
            #pragma unroll
            for (int r = 0; r < 4; ++r) {
                int row_l = 16*w + lq*4 + r;
                int gr = rbase + row_l;
                unsigned short xu = XTg[((size_t)b*XTR + c)*NN + gr];
                float xr = (float)(*(const __bf16*)&xu);
                s_A[row_l*168 + c]      = xu;
                s_A[row_l*168 + 66 + c] = f2b((acc[k][r] + xr) * rinv[r]);
            }
        }
    }

    // stage B half 0 direct into buf0; load half 1 -> regs
    for (int i = t; i < 1600; i += 256) {
        int cc = i/20, kc = i - cc*20;
        int d = (cc >> 4), oo = cc & 15;
        *(uint4*)&s_B[cc*168 + kc*8] = *(const uint4*)&BcT[(size_t)(d*O + oo)*KP + kc*8];
    }
    uint4 pr[7];
    loadB(BcT, O, 0, 1, t, pr);
    __syncthreads();

    // hoisted invariants (s_A immutable from here; ne2 rows fixed per thread)
    bf16x8 af[5];
    #pragma unroll
    for (int kc = 0; kc < 5; ++kc)
        af[kc] = *(const bf16x8*)&s_A[(16*w + ln)*168 + kc*32 + lq*8];
    float nepr[4][10];
    #pragma unroll
    for (int r = 0; r < 4; ++r) {
        int n = rbase + 16*w + lq*4 + r;
        #pragma unroll
        for (int d = 0; d < 10; ++d) nepr[r][d] = ne2[(size_t)n*ED + d];
    }

    // ================= GEMM PHASE: pipelined halves =================
    const int NH = (O/16)*2;
    int gcur = 0;
    float part[4];
    for (int hh = 0; hh < NH; ++hh) {
        int h = hh & 1, o0 = (hh >> 1)*16, o = o0 + ln;

        if (hh + 1 < NH) writeB(s_B + (gcur^1)*13440, t, pr);
        if (hh + 2 < NH) loadB(BcT, O, ((hh+2) >> 1)*16, (hh+2) & 1, t, pr);

        f32x4 gac[5];
        #pragma unroll
        for (int c = 0; c < 5; ++c) gac[c] = (f32x4){0.f,0.f,0.f,0.f};
        const unsigned short* sb = s_B + gcur*13440;
        #pragma unroll
        for (int kc = 0; kc < 5; ++kc) {
            #pragma unroll
            for (int ct = 0; ct < 5; ++ct) {
                bf16x8 bf = *(const bf16x8*)&sb[(ct*16 + ln)*168 + kc*32 + lq*8];
                gac[ct] = __builtin_amdgcn_mfma_f32_16x16x32_bf16(af[kc], bf, gac[ct], 0, 0, 0);
            }
        }

        // fold this half (R7/R8-validated FP order)
        #pragma unroll
        for (int r = 0; r < 4; ++r) {
            int row_l = 16*w + lq*4 + r;
            int n = rbase + row_l;
            size_t rowG = (size_t)b*NN + n;
            float val = (h == 0) ? biasP[(size_t)n*O + o] : part[r];
            #pragma unroll
            for (int d = 0; d < 5; ++d) val += nepr[r][h*5 + d] * gac[d][r];
            if (h == 0) {
                part[r] = val;
            } else {
                if (MODE == 0) {
                    float sv = 1.f/(1.f + __expf(-val));
                    if (o < 64) {
                        float zst = sv * state[rowG*DOUT + o];
                        XT1[((size_t)b*XTR + 2 + o)*NN + n] = f2b(zst);
                    } else {
                        rbuf[rowG*DOUT + (o - 64)] = sv;
                    }
                } else {
                    float hc = tanhf(val);
                    float rg = rbuf[rowG*DOUT + o];
                    float st = state[rowG*DOUT + o];
                    out[rowG*DOUT + o] = rg*st + (1.f - rg)*hc;
                }
            }
        }
        __syncthreads();
        gcur ^= 1;
    }
}

// ---------------------------------------------------------------------------
extern "C" void kernel_launch(void* const* d_in, const int* in_sizes, int n_in,
                              void* d_out, int out_size, void* d_ws, size_t ws_size,
                              hipStream_t stream)
{
    const float* x      = (const float*)d_in[0];
    const float* state  = (const float*)d_in[1];
    const float* ne0    = (const float*)d_in[2];
    const float* ne1    = (const float*)d_in[3];
    const float* ne2    = (const float*)d_in[4];
    const float* f1w1   = (const float*)d_in[5];
    const float* f1b1   = (const float*)d_in[6];
    const float* f1w2   = (const float*)d_in[7];
    const float* f1b2   = (const float*)d_in[8];
    const float* f1w3   = (const float*)d_in[9];
    const float* f1b3   = (const float*)d_in[10];
    const float* f2w1   = (const float*)d_in[11];
    const float* f2b1   = (const float*)d_in[12];
    const float* f2w2   = (const float*)d_in[13];
    const float* f2b2   = (const float*)d_in[14];
    const float* f2w3   = (const float*)d_in[15];
    const float* f2b3   = (const float*)d_in[16];
    const float* gate_w = (const float*)d_in[17];
    const float* gate_b = (const float*)d_in[18];
    const float* upd_w  = (const float*)d_in[19];
    const float* upd_b  = (const float*)d_in[20];

    unsigned short* nv1b = (unsigned short*)d_ws;
    unsigned short* nv2b = nv1b + (size_t)BB*NN*TD;
    unsigned short* XT0  = nv2b + (size_t)BB*NN*TD;
    unsigned short* XT1  = XT0  + (size_t)BB*XTR*NN;
    unsigned short* BcTg = XT1  + (size_t)BB*XTR*NN;
    unsigned short* BcTu = BcTg + (size_t)1280*KP;
    float* biasG = (float*)(BcTu + (size_t)640*KP);
    float* biasU = biasG + (size_t)NN*OG;
    float* rbuf  = biasU + (size_t)NN*OU;
    float* out   = (float*)d_out;

    k_pre<<<dim3(2608), 256, 0, stream>>>(x, state, ne0, ne1, ne2,
        f1w1, f1b1, f1w2, f1b2, f1w3, f1b3,
        f2w1, f2b1, f2w2, f2b2, f2w3, f2b3,
        gate_w, gate_b, upd_w, upd_b,
        nv1b, nv2b, XT0, XT1, BcTg, BcTu, biasG, biasU);

    k_fused<OG,0><<<dim3(512), 256, 0, stream>>>(nv1b, nv2b, XT0, BcTg, ne2,
                                                 biasG, state, XT1, rbuf, nullptr);

    k_fused<OU,1><<<dim3(512), 256, 0, stream>>>(nv1b, nv2b, XT1, BcTu, ne2,
                                                 biasU, state, nullptr, rbuf, out);
}

// Round 11
// 221.365 us; speedup vs baseline: 1.3466x; 1.3466x over previous
//
#include <hip/hip_runtime.h>
#include <math.h>

#define BB   32      // batch
#define NN   1024    // nodes
#define DIN  2
#define DOUT 64
#define CIN  66      // DIN + DOUT
#define TD   32
#define ED   10
#define OG   128     // 2*DOUT (gate out)
#define OU   64      // upd out
#define KP   160     // padded K for the einsum GEMM (132 real)
#define XTR  80      // XT rows per batch (68 data + 12 zero pad)

typedef __bf16 bf16x8 __attribute__((ext_vector_type(8)));
typedef float  f32x4  __attribute__((ext_vector_type(4)));
typedef short  s16x8  __attribute__((ext_vector_type(8)));

__device__ __forceinline__ unsigned short f2b(float f) {
    __bf16 h = (__bf16)f;
    return *(unsigned short*)&h;
}

// pack two f32 -> two bf16 (RNE), lo in low half
__device__ __forceinline__ unsigned int cvt_pk_bf16(float lo, float hi) {
    unsigned int r;
    asm("v_cvt_pk_bf16_f32 %0, %1, %2" : "=v"(r) : "v"(lo), "v"(hi));
    return r;
}
// a' = {a.lo32, b.lo32}; b' = {a.hi32, b.hi32}
__device__ __forceinline__ void perm32swap(unsigned int& a, unsigned int& b) {
    asm("v_permlane32_swap_b32 %0, %1" : "+v"(a), "+v"(b));
}
// a' = {a.r0, b.r0, a.r2, b.r2}; b' = {a.r1, b.r1, a.r3, b.r3} (16-lane rows)
__device__ __forceinline__ void perm16swap(unsigned int& a, unsigned int& b) {
    asm("v_permlane16_swap_b32 %0, %1" : "+v"(a), "+v"(b));
}

// ---------------------------------------------------------------------------
// K_PRE (R2-exact): heterogeneous preprocessing, one dispatch. FROZEN.
// ---------------------------------------------------------------------------
__global__ __launch_bounds__(256) void k_pre(
    const float* __restrict__ x, const float* __restrict__ state,
    const float* __restrict__ ne0, const float* __restrict__ ne1,
    const float* __restrict__ ne2,
    const float* __restrict__ w11, const float* __restrict__ b11,
    const float* __restrict__ w12, const float* __restrict__ b12,
    const float* __restrict__ w13, const float* __restrict__ b13,
    const float* __restrict__ w21, const float* __restrict__ b21,
    const float* __restrict__ w22, const float* __restrict__ b22,
    const float* __restrict__ w23, const float* __restrict__ b23,
    const float* __restrict__ gate_w, const float* __restrict__ gate_b,
    const float* __restrict__ upd_w, const float* __restrict__ upd_b,
    unsigned short* __restrict__ nv1b, unsigned short* __restrict__ nv2b,
    unsigned short* __restrict__ XT0, unsigned short* __restrict__ XT1,
    unsigned short* __restrict__ BcTg, unsigned short* __restrict__ BcTu,
    float* __restrict__ biasG, float* __restrict__ biasU)
{
    __shared__ float sw[2408];
    __shared__ unsigned short st[68*72];
    int blk = blockIdx.x;
    int t = threadIdx.x;

    if (blk < 128) {
        const int oW1 = 0, oB1 = 1056, oW2 = 1072, oB2 = 1104, oW3 = 1108, oB3 = 1172, F2 = 1204;
        for (int i = t; i < 1056; i += 256) { sw[oW1+i] = w11[i]; sw[F2+oW1+i] = w21[i]; }
        if (t < 16) { sw[oB1+t] = b11[t]; sw[F2+oB1+t] = b21[t]; }
        if (t < 32) { sw[oW2+t] = w12[t]; sw[F2+oW2+t] = w22[t]; }
        if (t < 2)  { sw[oB2+t] = b12[t]; sw[F2+oB2+t] = b22[t]; }
        if (t < 64) { sw[oW3+t] = w13[t]; sw[F2+oW3+t] = w23[t]; }
        if (t >= 64 && t < 96) { sw[oB3+t-64] = b13[t-64]; sw[F2+oB3+t-64] = b23[t-64]; }
        __syncthreads();

        int p = blk*256 + t;
        int b = p >> 10;

        float h1a[16], h1b[16];
        #pragma unroll
        for (int j = 0; j < 16; ++j) { h1a[j] = sw[oB1+j]; h1b[j] = sw[F2+oB1+j]; }
        for (int i = 0; i < CIN; ++i) {
            float v = (i < DIN) ? x[(size_t)p*DIN + i] : state[(size_t)p*DOUT + (i-DIN)];
            #pragma unroll
            for (int jq = 0; jq < 4; ++jq) {
                float4 wa = *(const float4*)&sw[oW1 + i*16 + jq*4];
                float4 wb = *(const float4*)&sw[F2 + oW1 + i*16 + jq*4];
                h1a[jq*4+0] += v*wa.x; h1a[jq*4+1] += v*wa.y;
                h1a[jq*4+2] += v*wa.z; h1a[jq*4+3] += v*wa.w;
                h1b[jq*4+0] += v*wb.x; h1b[jq*4+1] += v*wb.y;
                h1b[jq*4+2] += v*wb.z; h1b[jq*4+3] += v*wb.w;
            }
        }
        #pragma unroll
        for (int j = 0; j < 16; ++j) {
            h1a[j] = 1.f/(1.f + __expf(-h1a[j]));
            h1b[j] = 1.f/(1.f + __expf(-h1b[j]));
        }
        float h2a0 = sw[oB2+0], h2a1 = sw[oB2+1];
        float h2b0 = sw[F2+oB2+0], h2b1 = sw[F2+oB2+1];
        #pragma unroll
        for (int i = 0; i < 16; ++i) {
            h2a0 += h1a[i]*sw[oW2 + i*2 + 0];
            h2a1 += h1a[i]*sw[oW2 + i*2 + 1];
            h2b0 += h1b[i]*sw[F2+oW2 + i*2 + 0];
            h2b1 += h1b[i]*sw[F2+oW2 + i*2 + 1];
        }
        h2a0 = 1.f/(1.f + __expf(-h2a0)); h2a1 = 1.f/(1.f + __expf(-h2a1));
        h2b0 = 1.f/(1.f + __expf(-h2b0)); h2b1 = 1.f/(1.f + __expf(-h2b1));

        const float* pn0 = ne0 + b*TD;
        const float* pn1 = ne1 + b*TD;
        #pragma unroll
        for (int jq = 0; jq < 8; ++jq) {
            float4 ba  = *(const float4*)&sw[oB3 + jq*4];
            float4 wa0 = *(const float4*)&sw[oW3 + jq*4];
            float4 wa1 = *(const float4*)&sw[oW3 + 32 + jq*4];
            float4 bb2 = *(const float4*)&sw[F2+oB3 + jq*4];
            float4 wb0 = *(const float4*)&sw[F2+oW3 + jq*4];
            float4 wb1 = *(const float4*)&sw[F2+oW3 + 32 + jq*4];
            float4 n0 = *(const float4*)&pn0[jq*4];
            float4 n1 = *(const float4*)&pn1[jq*4];
            ushort4 u1, u2;
            u1.x = f2b(tanhf(n0.x*(ba.x + h2a0*wa0.x + h2a1*wa1.x)));
            u1.y = f2b(tanhf(n0.y*(ba.y + h2a0*wa0.y + h2a1*wa1.y)));
            u1.z = f2b(tanhf(n0.z*(ba.z + h2a0*wa0.z + h2a1*wa1.z)));
            u1.w = f2b(tanhf(n0.w*(ba.w + h2a0*wa0.w + h2a1*wa1.w)));
            u2.x = f2b(tanhf(n1.x*(bb2.x + h2b0*wb0.x + h2b1*wb1.x)));
            u2.y = f2b(tanhf(n1.y*(bb2.y + h2b0*wb0.y + h2b1*wb1.y)));
            u2.z = f2b(tanhf(n1.z*(bb2.z + h2b0*wb0.z + h2b1*wb1.z)));
            u2.w = f2b(tanhf(n1.w*(bb2.w + h2b0*wb0.w + h2b1*wb1.w)));
            *(ushort4*)&nv1b[(size_t)p*TD + jq*4] = u1;
            *(ushort4*)&nv2b[(size_t)p*TD + jq*4] = u2;
        }
    } else if (blk < 640) {
        int idx = blk - 128;
        int b = idx >> 4, m0 = (idx & 15)*64;
        for (int i = t; i < 1024; i += 256) {
            int m = i >> 4, cq = i & 15;
            size_t base = (size_t)b*NN + m0 + m;
            float4 v = *(const float4*)&state[base*DOUT + cq*4];
            st[(2 + cq*4 + 0)*72 + m] = f2b(v.x);
            st[(2 + cq*4 + 1)*72 + m] = f2b(v.y);
            st[(2 + cq*4 + 2)*72 + m] = f2b(v.z);
            st[(2 + cq*4 + 3)*72 + m] = f2b(v.w);
        }
        if (t < 128) {
            int m = t >> 1, c = t & 1;
            st[c*72 + m] = f2b(x[((size_t)b*NN + m0 + m)*DIN + c]);
        }
        __syncthreads();
        const unsigned int ONE2 = 0x3F803F80u;
        for (int i = t; i < XTR*8; i += 256) {
            int c = i >> 3, ch = i & 7;
            uint4 v;
            if (c < 66)      v = *(const uint4*)&st[c*72 + ch*8];
            else if (c == 66) v = make_uint4(ONE2, ONE2, ONE2, ONE2);
            else              v = make_uint4(0, 0, 0, 0);
            *(uint4*)&XT0[((size_t)b*XTR + c)*NN + m0 + ch*8] = v;
            if (c < 2 || c >= 66)
                *(uint4*)&XT1[((size_t)b*XTR + c)*NN + m0 + ch*8] = v;
        }
    } else if (blk < 1840) {
        int tid = (blk - 640)*256 + t;
        int c = tid / KP, k = tid - c*KP;
        const float* pool; int O, cc; unsigned short* dst;
        if (c < 1280) { pool = gate_w; O = OG; cc = c;        dst = BcTg; }
        else          { pool = upd_w;  O = OU; cc = c - 1280; dst = BcTu; }
        int d = cc / O, o = cc - d*O;
        float v = 0.f;
        if (k < 132) {
            int kp = (k < 66) ? 0 : 1;
            int i  = (k < 66) ? k : k - 66;
            v = pool[(size_t)((d*4 + kp)*CIN + i)*O + o]
              + pool[(size_t)((d*4 + kp + 2)*CIN + i)*O + o];
        }
        dst[(size_t)cc*KP + k] = f2b(v);
    } else {
        int i = (blk - 1840)*256 + t;
        int n = i / 192, j = i - n*192;
        float v = 0.f;
        if (j < 128) {
            #pragma unroll
            for (int d = 0; d < ED; ++d) v += ne2[(size_t)n*ED + d]*gate_b[d*OG + j];
            biasG[(size_t)n*OG + j] = v;
        } else {
            int o = j - 128;
            #pragma unroll
            for (int d = 0; d < ED; ++d) v += ne2[(size_t)n*ED + d]*upd_b[d*OU + o];
            biasU[(size_t)n*OU + o] = v;
        }
    }
}

// ---------------------------------------------------------------------------
// K_AAPPLY v8 (R2-proven): LDS-staged + depth-2 register prefetch, 1
// barrier/iter; S^T swapped-MFMA; in-register P transpose (cvt_pk+permlane);
// shfl rowsum. The session's one real structural win. FROZEN.
// ---------------------------------------------------------------------------
__global__ __launch_bounds__(256) void k_aapply(
    const unsigned short* __restrict__ nv1b, const unsigned short* __restrict__ nv2b,
    const unsigned short* __restrict__ XTg, unsigned short* __restrict__ A)
{
    __shared__ unsigned short s_nv1c[2][2560];   // [64][40]
    __shared__ unsigned short s_nv2c[2][2560];
    __shared__ unsigned short s_xt[2][5760];     // [80][72]

    int t = threadIdx.x;
    int id = blockIdx.x;
    int b = id & 31, rbase = (id >> 5)*64;
    int w = t >> 6, lane = t & 63, lq = lane >> 4, ln = lane & 15;

    // row fragments: wave w owns rows rbase+16w .. +15 (one-time global load)
    bf16x8 a1 = *(const bf16x8*)&nv1b[((size_t)b*NN + rbase + 16*w + ln)*TD + lq*8];
    s16x8 a2s = *(const s16x8*)&nv2b[((size_t)b*NN + rbase + 16*w + ln)*TD + lq*8];
    const s16x8 sgn = {(short)0x8000,(short)0x8000,(short)0x8000,(short)0x8000,
                       (short)0x8000,(short)0x8000,(short)0x8000,(short)0x8000};
    a2s ^= sgn;
    bf16x8 a2n = (bf16x8)a2s;          // -nv2 row fragment

    // staging geometry: 256 threads stage 64x32 nv1 + 64x32 nv2 + 80x64 xt
    const unsigned short* pnv1 = nv1b + (size_t)b*NN*TD;
    const unsigned short* pnv2 = nv2b + (size_t)b*NN*TD;
    const unsigned short* pxt  = XTg  + (size_t)b*XTR*NN;
    int nnode = t >> 2;          // 0..63
    int nch   = (t & 3)*8;       // short offset 0,8,16,24
    int xc    = t >> 3;          // 0..31
    int xch   = (t & 7)*8;       // short offset 0..56

    uint4 q0, q1, r0, r1, r2;

    f32x4 acc[5];
    #pragma unroll
    for (int k = 0; k < 5; ++k) acc[k] = (f32x4){0.f,0.f,0.f,0.f};
    const f32x4 zero4 = {0.f,0.f,0.f,0.f};
    union U8 { unsigned int u[4]; bf16x8 v; };

    // ---- prologue: tile 0 -> buf0 (direct), tile 1 -> regs
    q0 = *(const uint4*)&pnv1[(size_t)nnode*TD + nch];
    q1 = *(const uint4*)&pnv2[(size_t)nnode*TD + nch];
    r0 = *(const uint4*)&pxt[(size_t)xc*NN + xch];
    r1 = *(const uint4*)&pxt[(size_t)(xc+32)*NN + xch];
    if (t < 128) r2 = *(const uint4*)&pxt[(size_t)(xc+64)*NN + xch];
    *(uint4*)&s_nv1c[0][nnode*40 + nch] = q0;
    *(uint4*)&s_nv2c[0][nnode*40 + nch] = q1;
    *(uint4*)&s_xt[0][xc*72 + xch] = r0;
    *(uint4*)&s_xt[0][(xc+32)*72 + xch] = r1;
    if (t < 128) *(uint4*)&s_xt[0][(xc+64)*72 + xch] = r2;
    q0 = *(const uint4*)&pnv1[(size_t)(64 + nnode)*TD + nch];
    q1 = *(const uint4*)&pnv2[(size_t)(64 + nnode)*TD + nch];
    r0 = *(const uint4*)&pxt[(size_t)xc*NN + 64 + xch];
    r1 = *(const uint4*)&pxt[(size_t)(xc+32)*NN + 64 + xch];
    if (t < 128) r2 = *(const uint4*)&pxt[(size_t)(xc+64)*NN + 64 + xch];
    __syncthreads();

    int cur = 0;
    for (int mb = 0; mb < NN; mb += 64) {
        // ---- store tile t+1 (regs are one full iteration old -> no stall)
        if (mb + 64 < NN) {
            *(uint4*)&s_nv1c[cur^1][nnode*40 + nch] = q0;
            *(uint4*)&s_nv2c[cur^1][nnode*40 + nch] = q1;
            *(uint4*)&s_xt[cur^1][xc*72 + xch] = r0;
            *(uint4*)&s_xt[cur^1][(xc+32)*72 + xch] = r1;
            if (t < 128) *(uint4*)&s_xt[cur^1][(xc+64)*72 + xch] = r2;
        }
        // ---- issue tile t+2 loads early (latency hidden under compute)
        if (mb + 128 < NN) {
            int mb2 = mb + 128;
            q0 = *(const uint4*)&pnv1[(size_t)(mb2 + nnode)*TD + nch];
            q1 = *(const uint4*)&pnv2[(size_t)(mb2 + nnode)*TD + nch];
            r0 = *(const uint4*)&pxt[(size_t)xc*NN + mb2 + xch];
            r1 = *(const uint4*)&pxt[(size_t)(xc+32)*NN + mb2 + xch];
            if (t < 128) r2 = *(const uint4*)&pxt[(size_t)(xc+64)*NN + mb2 + xch];
        }

        // ---- S^T phase: lane (lq,ln) holds S[row ln][col jj*16+lq*4+r]
        unsigned int u[4][2];
        #pragma unroll
        for (int jj = 0; jj < 4; ++jj) {
            bf16x8 b2 = *(const bf16x8*)&s_nv2c[cur][(jj*16 + ln)*40 + lq*8];
            bf16x8 b1 = *(const bf16x8*)&s_nv1c[cur][(jj*16 + ln)*40 + lq*8];
            f32x4 s = __builtin_amdgcn_mfma_f32_16x16x32_bf16(b2, a1,  zero4, 0, 0, 0);
            s       = __builtin_amdgcn_mfma_f32_16x16x32_bf16(b1, a2n, s,     0, 0, 0);
            u[jj][0] = cvt_pk_bf16(fmaxf(s[0], 0.f), fmaxf(s[1], 0.f));
            u[jj][1] = cvt_pk_bf16(fmaxf(s[2], 0.f), fmaxf(s[3], 0.f));
        }

        // ---- in-register transpose to A-fragments (k = lq*8 + j)
        unsigned int w00 = u[0][0], w20 = u[1][0]; perm32swap(w00, w20); perm16swap(w00, w20);
        unsigned int w01 = u[0][1], w21 = u[1][1]; perm32swap(w01, w21); perm16swap(w01, w21);
        unsigned int x00 = u[2][0], x20 = u[3][0]; perm32swap(x00, x20); perm16swap(x00, x20);
        unsigned int x01 = u[2][1], x21 = u[3][1]; perm32swap(x01, x21); perm16swap(x01, x21);
        U8 p0, p1;
        p0.u[0] = w00; p0.u[1] = w01; p0.u[2] = w20; p0.u[3] = w21;   // P cols mb+0..31
        p1.u[0] = x00; p1.u[1] = x01; p1.u[2] = x20; p1.u[3] = x21;   // P cols mb+32..63
        bf16x8 pa0 = p0.v, pa1 = p1.v;

        // ---- PV phase from staged XT
        #pragma unroll
        for (int k = 0; k < 5; ++k) {
            bf16x8 xb0 = *(const bf16x8*)&s_xt[cur][(k*16 + ln)*72 +      lq*8];
            bf16x8 xb1 = *(const bf16x8*)&s_xt[cur][(k*16 + ln)*72 + 32 + lq*8];
            acc[k] = __builtin_amdgcn_mfma_f32_16x16x32_bf16(pa0, xb0, acc[k], 0, 0, 0);
            acc[k] = __builtin_amdgcn_mfma_f32_16x16x32_bf16(pa1, xb1, acc[k], 0, 0, 0);
        }

        __syncthreads();
        cur ^= 1;
    }

    // rowsum = out col 66 -> tile 4, lane col ln==2; broadcast within 16-lane group
    float rinv[4];
    #pragma unroll
    for (int r = 0; r < 4; ++r) {
        float rs = __shfl(acc[4][r], (lane & 48) | 2, 64);
        rinv[r] = 1.0f / (1.0f + rs);
    }

    #pragma unroll
    for (int k = 0; k < 5; ++k) {
        int c = k*16 + ln;
        if (c < CIN) {
            #pragma unroll
            for (int r = 0; r < 4; ++r) {
                int gr = rbase + 16*w + lq*4 + r;
                size_t rowG = (size_t)b*NN + gr;
                unsigned short xu = XTg[((size_t)b*XTR + c)*NN + gr];
                float xr = (float)(*(const __bf16*)&xu);
                A[rowG*KP + c]      = xu;
                A[rowG*KP + 66 + c] = f2b((acc[k][r] + xr) * rinv[r]);
            }
        }
    }
    for (int i = t; i < 64*28; i += 256) {
        int rr = i / 28, cc = 132 + (i - 28*(i/28));
        A[((size_t)b*NN + rbase + rr)*KP + cc] = 0;
    }
}

// ---------------------------------------------------------------------------
// K_GEMM v5 (R2-exact): half-B resident (26.9 KB), two halves with restage
// barriers; ne2/bias direct from global; wave = 32 rows. FROZEN.
// ---------------------------------------------------------------------------
template<int O, int MODE>
__global__ __launch_bounds__(256) void k_gemm(
    const unsigned short* __restrict__ A, const unsigned short* __restrict__ BcT,
    const float* __restrict__ ne2, const float* __restrict__ biasP,
    const float* __restrict__ state, unsigned short* __restrict__ XT1,
    float* __restrict__ rbuf, float* __restrict__ out)
{
    __shared__ unsigned short s_b[80*168];

    int t = threadIdx.x;
    int w = t >> 6, lane = t & 63, lq = lane >> 4, ln = lane & 15;
    int o0 = blockIdx.y*16;
    int rowBlock = blockIdx.x*128;
    int rowW = rowBlock + w*32;

    f32x4 acc[2][2][5];
    #pragma unroll
    for (int h = 0; h < 2; ++h)
        #pragma unroll
        for (int f = 0; f < 2; ++f)
            #pragma unroll
            for (int c = 0; c < 5; ++c) acc[h][f][c] = (f32x4){0.f,0.f,0.f,0.f};

    #pragma unroll
    for (int h = 0; h < 2; ++h) {
        if (h) __syncthreads();
        for (int i = t; i < 1600; i += 256) {
            int cc = i / 20, kc = i - cc*20;
            int d = h*5 + (cc >> 4), oo = cc & 15;
            *(uint4*)&s_b[cc*168 + kc*8] =
                *(const uint4*)&BcT[(size_t)(d*O + o0 + oo)*KP + kc*8];
        }
        __syncthreads();

        #pragma unroll
        for (int kc = 0; kc < 5; ++kc) {
            bf16x8 af0 = *(const bf16x8*)&A[(size_t)(rowW      + ln)*KP + kc*32 + lq*8];
            bf16x8 af1 = *(const bf16x8*)&A[(size_t)(rowW + 16 + ln)*KP + kc*32 + lq*8];
            #pragma unroll
            for (int ct = 0; ct < 5; ++ct) {
                bf16x8 bf = *(const bf16x8*)&s_b[(ct*16 + ln)*168 + kc*32 + lq*8];
                acc[h][0][ct] = __builtin_amdgcn_mfma_f32_16x16x32_bf16(af0, bf, acc[h][0][ct], 0, 0, 0);
                acc[h][1][ct] = __builtin_amdgcn_mfma_f32_16x16x32_bf16(af1, bf, acc[h][1][ct], 0, 0, 0);
            }
        }
    }

    int o = o0 + ln;
    #pragma unroll
    for (int f = 0; f < 2; ++f) {
        #pragma unroll
        for (int r = 0; r < 4; ++r) {
            int row_l = w*32 + 16*f + lq*4 + r;
            size_t rowG = (size_t)rowBlock + row_l;
            int n = (int)(rowG & (NN - 1));
            int bb = (int)(rowG >> 10);
            const float* nep = &ne2[(size_t)n*ED];
            float val = biasP[(size_t)n*O + o];
            #pragma unroll
            for (int d = 0; d < 5; ++d) val += nep[d]     * acc[0][f][d][r];
            #pragma unroll
            for (int d = 0; d < 5; ++d) val += nep[5 + d] * acc[1][f][d][r];
            if (MODE == 0) {
                float sv = 1.f/(1.f + __expf(-val));
                if (o0 < 64) {
                    float zst = sv * state[rowG*DOUT + o];
                    XT1[((size_t)bb*XTR + 2 + o)*NN + n] = f2b(zst);
                } else {
                    rbuf[rowG*DOUT + (o - 64)] = sv;
                }
            } else {
                float hc = tanhf(val);
                float rg = rbuf[rowG*DOUT + o];
                float st = state[rowG*DOUT + o];
                out[rowG*DOUT + o] = rg*st + (1.f - rg)*hc;
            }
        }
    }
}

// ---------------------------------------------------------------------------
extern "C" void kernel_launch(void* const* d_in, const int* in_sizes, int n_in,
                              void* d_out, int out_size, void* d_ws, size_t ws_size,
                              hipStream_t stream)
{
    const float* x      = (const float*)d_in[0];
    const float* state  = (const float*)d_in[1];
    const float* ne0    = (const float*)d_in[2];
    const float* ne1    = (const float*)d_in[3];
    const float* ne2    = (const float*)d_in[4];
    const float* f1w1   = (const float*)d_in[5];
    const float* f1b1   = (const float*)d_in[6];
    const float* f1w2   = (const float*)d_in[7];
    const float* f1b2   = (const float*)d_in[8];
    const float* f1w3   = (const float*)d_in[9];
    const float* f1b3   = (const float*)d_in[10];
    const float* f2w1   = (const float*)d_in[11];
    const float* f2b1   = (const float*)d_in[12];
    const float* f2w2   = (const float*)d_in[13];
    const float* f2b2   = (const float*)d_in[14];
    const float* f2w3   = (const float*)d_in[15];
    const float* f2b3   = (const float*)d_in[16];
    const float* gate_w = (const float*)d_in[17];
    const float* gate_b = (const float*)d_in[18];
    const float* upd_w  = (const float*)d_in[19];
    const float* upd_b  = (const float*)d_in[20];

    unsigned short* nv1b = (unsigned short*)d_ws;
    unsigned short* nv2b = nv1b + (size_t)BB*NN*TD;
    unsigned short* XT0  = nv2b + (size_t)BB*NN*TD;
    unsigned short* XT1  = XT0  + (size_t)BB*XTR*NN;
    unsigned short* A    = XT1  + (size_t)BB*XTR*NN;
    unsigned short* BcTg = A    + (size_t)BB*NN*KP;
    unsigned short* BcTu = BcTg + (size_t)1280*KP;
    float* biasG = (float*)(BcTu + (size_t)640*KP);
    float* biasU = biasG + (size_t)NN*OG;
    float* rbuf  = biasU + (size_t)NN*OU;
    float* out   = (float*)d_out;

    k_pre<<<dim3(2608), 256, 0, stream>>>(x, state, ne0, ne1, ne2,
        f1w1, f1b1, f1w2, f1b2, f1w3, f1b3,
        f2w1, f2b1, f2w2, f2b2, f2w3, f2b3,
        gate_w, gate_b, upd_w, upd_b,
        nv1b, nv2b, XT0, XT1, BcTg, BcTu, biasG, biasU);

    k_aapply<<<dim3(512), 256, 0, stream>>>(nv1b, nv2b, XT0, A);

    k_gemm<OG,0><<<dim3(BB*NN/128, 8), 256, 0, stream>>>(A, BcTg, ne2, biasG,
                                                         state, XT1, rbuf, nullptr);

    k_aapply<<<dim3(512), 256, 0, stream>>>(nv1b, nv2b, XT1, A);

    k_gemm<OU,1><<<dim3(BB*NN/128, 4), 256, 0, stream>>>(A, BcTu, ne2, biasU,
                                                         state, nullptr, rbuf, out);
}